// Round 1
// baseline (210.178 us; speedup 1.0000x reference)
//
#include <hip/hip_runtime.h>

typedef __attribute__((ext_vector_type(8))) short short8;
typedef __attribute__((ext_vector_type(4))) short short4v;
typedef __attribute__((ext_vector_type(4))) float float4v;

#define T_SEQ 2048
#define CDIM 1024
#define NHEAD 16
#define HDIM 64
#define PROW 72  // proj LDS row stride (shorts), BK=64 + pad

__device__ __forceinline__ unsigned short f2bf(float f) {
    unsigned u = __builtin_bit_cast(unsigned, f);
    u += 0x7FFF + ((u >> 16) & 1);
    return (unsigned short)(u >> 16);
}

// async global->LDS, 16B per lane. LDS dest must be wave-uniform base;
// HW writes lane l at base + l*16B. Global src is per-lane.
__device__ __forceinline__ void gload16(const unsigned short* g,
                                        unsigned short* l) {
    __builtin_amdgcn_global_load_lds(
        (const __attribute__((address_space(1))) unsigned int*)g,
        (__attribute__((address_space(3))) unsigned int*)l, 16, 0, 0);
}

// ---------------- conversion kernels ----------------
__global__ __launch_bounds__(256) void convert_f32_bf16_vec(
    const float* __restrict__ in, unsigned short* __restrict__ out) {
    int i = blockIdx.x * 256 + threadIdx.x;
    float4 v = ((const float4*)in)[i];
    ushort4 o;
    o.x = f2bf(v.x); o.y = f2bf(v.y); o.z = f2bf(v.z); o.w = f2bf(v.w);
    ((ushort4*)out)[i] = o;
}

// in [K][N] fp32 -> out [N][K] bf16
__global__ __launch_bounds__(256) void transpose_f32_bf16(
    const float* __restrict__ in, unsigned short* __restrict__ out, int K, int N) {
    __shared__ float tile[32][33];
    int kb = blockIdx.x * 32, nb = blockIdx.y * 32;
    int tx = threadIdx.x & 31, ty = threadIdx.x >> 5;  // ty 0..7
    for (int r = 0; r < 4; r++)
        tile[ty + r * 8][tx] = in[(size_t)(kb + ty + r * 8) * N + nb + tx];
    __syncthreads();
    for (int r = 0; r < 4; r++)
        out[(size_t)(nb + ty + r * 8) * K + kb + tx] = f2bf(tile[tx][ty + r * 8]);
}

// ---------------- QKV GEMM: 128x128, BK=32, m97 structure -----------------
// global_load_lds width-16 staging into a single linear [128][32] LDS tile,
// 2 barriers per K-step. Staging VALU/ds_write eliminated vs reg-staged
// version (m151: gload_lds 874 TF vs reg-staged 646 TF at this tile).
// Linear layout is required by global_load_lds (wave-uniform base + lane*16B)
// so no pad: accept ~8-way ds_read_b128 conflict (off critical path at
// 2-phase schedule; T2 regime gate).
__global__ __launch_bounds__(256) void gemm_qkv(
    const unsigned short* __restrict__ A, const unsigned short* __restrict__ Bt,
    unsigned short* __restrict__ dK, unsigned short* __restrict__ dQ,
    unsigned short* __restrict__ dV) {
    const int K = 1024;
    __shared__ unsigned short sA[128 * 32];
    __shared__ unsigned short sB[128 * 32];
    int tid = threadIdx.x, wave = tid >> 6, lane = tid & 63;
    int quad = lane >> 4, l16 = lane & 15;
    int wm = wave >> 1, wn = wave & 1;
    int blockM = blockIdx.y * 128, blockN = blockIdx.x * 128;
    bool swapAB = (blockN >= 2048);  // V part: produce C^T

    const unsigned short* gA = A + (size_t)blockM * K;
    const unsigned short* gB = Bt + (size_t)blockN * K;

    // staging: wave w covers rows [w*32, w*32+32) of each tile via 2 gloads.
    // instr i: 16 rows; lane l -> row +(l>>2), col seg (l&3)*8 shorts.
    int srow = wave * 32 + (lane >> 2);
    int scol = (lane & 3) * 8;
    const unsigned short* pa0 = gA + (size_t)srow * K + scol;
    const unsigned short* pa1 = pa0 + (size_t)16 * K;
    const unsigned short* pb0 = gB + (size_t)srow * K + scol;
    const unsigned short* pb1 = pb0 + (size_t)16 * K;
    unsigned short* la0 = sA + (wave * 32) * 32;
    unsigned short* la1 = sA + (wave * 32 + 16) * 32;
    unsigned short* lb0 = sB + (wave * 32) * 32;
    unsigned short* lb1 = sB + (wave * 32 + 16) * 32;

    float4v acc[4][4] = {};
    int aoff = (wm * 64 + l16) * 32 + quad * 8;
    int boff = (wn * 64 + l16) * 32 + quad * 8;

    for (int kb = 0; kb < K; kb += 32) {
        gload16(pa0 + kb, la0);
        gload16(pa1 + kb, la1);
        gload16(pb0 + kb, lb0);
        gload16(pb1 + kb, lb1);
        __syncthreads();  // compiler drains vmcnt before s_barrier: LDS ready
        short8 af[4], bf[4];
        for (int i = 0; i < 4; i++)
            af[i] = *(const short8*)(sA + aoff + i * 16 * 32);
        for (int j = 0; j < 4; j++)
            bf[j] = *(const short8*)(sB + boff + j * 16 * 32);
        if (!swapAB) {
            for (int i = 0; i < 4; i++)
                for (int j = 0; j < 4; j++)
                    acc[i][j] = __builtin_amdgcn_mfma_f32_16x16x32_bf16(
                        af[i], bf[j], acc[i][j], 0, 0, 0);
        } else {
            for (int i = 0; i < 4; i++)
                for (int j = 0; j < 4; j++)
                    acc[i][j] = __builtin_amdgcn_mfma_f32_16x16x32_bf16(
                        bf[j], af[i], acc[i][j], 0, 0, 0);
        }
        __syncthreads();  // all reads done before next stage overwrites
    }

    if (!swapAB) {
        const float QSCL = 0.18033688011112042f;  // 0.125 * log2(e)
        for (int i = 0; i < 4; i++)
            for (int j = 0; j < 4; j++)
                for (int r = 0; r < 4; r++) {
                    int m = blockM + wm * 64 + i * 16 + quad * 4 + r;
                    int n = blockN + wn * 64 + j * 16 + l16;
                    int part = n >> 10, c = n & 1023;
                    int h = c >> 6, d = c & 63;
                    int bb = m >> 11, t = m & 2047;
                    int bh = bb * NHEAD + h;
                    if (part == 0) {
                        dK[(((size_t)bh * T_SEQ + t) << 6) + d] = f2bf(acc[i][j][r]);
                    } else {
                        dQ[(((size_t)bh * T_SEQ + t) << 6) + d] =
                            f2bf(acc[i][j][r] * QSCL);
                    }
                }
    } else {
        for (int i = 0; i < 4; i++)
            for (int j = 0; j < 4; j++)
                for (int r = 0; r < 4; r++) {
                    int n = blockN + wn * 64 + j * 16 + quad * 4 + r;
                    int m = blockM + wm * 64 + i * 16 + l16;
                    int c = n & 1023;
                    int h = c >> 6, d = c & 63;
                    int bb = m >> 11, t = m & 2047;
                    int bh = bb * NHEAD + h;
                    dV[((size_t)bh * HDIM + d) * T_SEQ + t] = f2bf(acc[i][j][r]);
                }
    }
}

// ---------------- proj GEMM: 64x64 tile, BK=64, reg-prefetch --------------
// kb-indexed staging addresses (immediate-offset friendly); PROW=72 pad.
__global__ __launch_bounds__(256) void gemm_proj(
    const unsigned short* __restrict__ A, const unsigned short* __restrict__ Bt,
    const float* __restrict__ bias, float* __restrict__ out) {
    const int K = 1024;
    const int NITER = K / 64;
    __shared__ unsigned short sA[2][64 * PROW];
    __shared__ unsigned short sB[2][64 * PROW];
    int tid = threadIdx.x, wave = tid >> 6, lane = tid & 63;
    int quad = lane >> 4, l16 = lane & 15;
    int wm = wave >> 1, wn = wave & 1;
    int blockM = blockIdx.y * 64, blockN = blockIdx.x * 64;

    int srow = tid >> 3;      // 0..31
    int sseg = tid & 7;       // 0..7
    const unsigned short* gA0 = A + (size_t)(blockM + srow) * K + sseg * 8;
    const unsigned short* gA1 = gA0 + (size_t)32 * K;
    const unsigned short* gB0 = Bt + (size_t)(blockN + srow) * K + sseg * 8;
    const unsigned short* gB1 = gB0 + (size_t)32 * K;
    int so0 = srow * PROW + sseg * 8;
    int so1 = (srow + 32) * PROW + sseg * 8;

    float4v acc[2][2] = {};
    uint4 ra0, ra1, rb0, rb1;

    ra0 = *(const uint4*)gA0; ra1 = *(const uint4*)gA1;
    rb0 = *(const uint4*)gB0; rb1 = *(const uint4*)gB1;
    *(uint4*)(sA[0] + so0) = ra0;
    *(uint4*)(sA[0] + so1) = ra1;
    *(uint4*)(sB[0] + so0) = rb0;
    *(uint4*)(sB[0] + so1) = rb1;

    int aoff = (wm * 32 + l16) * PROW + quad * 8;
    int boff = (wn * 32 + l16) * PROW + quad * 8;

    for (int it = 0; it < NITER; it++) {
        int cur = it & 1;
        __syncthreads();
        if (it + 1 < NITER) {
            int kb = (it + 1) * 64;
            ra0 = *(const uint4*)(gA0 + kb); ra1 = *(const uint4*)(gA1 + kb);
            rb0 = *(const uint4*)(gB0 + kb); rb1 = *(const uint4*)(gB1 + kb);
        }
        const unsigned short* cA = sA[cur];
        const unsigned short* cB = sB[cur];
        short8 af[2][2], bf[2][2];
        for (int i = 0; i < 2; i++)
            for (int k = 0; k < 2; k++)
                af[i][k] = *(const short8*)(cA + aoff + i * 16 * PROW + k * 32);
        for (int j = 0; j < 2; j++)
            for (int k = 0; k < 2; k++)
                bf[j][k] = *(const short8*)(cB + boff + j * 16 * PROW + k * 32);
        for (int i = 0; i < 2; i++)
            for (int j = 0; j < 2; j++) {
                acc[i][j] = __builtin_amdgcn_mfma_f32_16x16x32_bf16(
                    af[i][0], bf[j][0], acc[i][j], 0, 0, 0);
                acc[i][j] = __builtin_amdgcn_mfma_f32_16x16x32_bf16(
                    af[i][1], bf[j][1], acc[i][j], 0, 0, 0);
            }
        if (it + 1 < NITER) {
            int nxt = cur ^ 1;
            *(uint4*)(sA[nxt] + so0) = ra0;
            *(uint4*)(sA[nxt] + so1) = ra1;
            *(uint4*)(sB[nxt] + so0) = rb0;
            *(uint4*)(sB[nxt] + so1) = rb1;
        }
    }

    for (int i = 0; i < 2; i++)
        for (int j = 0; j < 2; j++)
            for (int r = 0; r < 4; r++) {
                int m = blockM + wm * 32 + i * 16 + quad * 4 + r;
                int n = blockN + wn * 32 + j * 16 + l16;
                out[(size_t)m * CDIM + n] = acc[i][j][r] + bias[n];
            }
}

// ---------------- flash attention v6: one q-tile per block ----------------
// Same inner structure as R7/R10 (fixed-max softmax, reg-prefetch dbuf) but
// the 2-pass pairing is split into the grid: (32 bh, 32 xt) = 1024 blocks =
// 4 blocks/CU, 16 waves/CU -> cross-block phase overlap. xt = 31 - y so the
// longest blocks dispatch first. Same-bh blocks share XCD (id % 8 == bh % 8).
__global__ __launch_bounds__(256) void attn_fwd(
    const unsigned short* __restrict__ Qp, const unsigned short* __restrict__ Kp,
    const unsigned short* __restrict__ Vt, unsigned short* __restrict__ att) {
    __shared__ unsigned short sK[2][64 * 72];
    __shared__ unsigned short sV[2][64 * 72];
    int tid = threadIdx.x, wave = tid >> 6, lane = tid & 63;
    int quad = lane >> 4, l16 = lane & 15;
    int bh = blockIdx.x;
    int bb = bh >> 4, h = bh & 15;
    size_t baseQ = (size_t)bh * T_SEQ * HDIM;  // [t][d]
    size_t baseV = (size_t)bh * HDIM * T_SEQ;  // [d][t]
    int row4 = tid >> 2, seg = tid & 3;

    int xt = 31 - blockIdx.y;
    int qb = xt * 64;
    int qrow = qb + wave * 16 + l16;

    const unsigned short* qr = Qp + baseQ + (size_t)qrow * HDIM;
    short8 qf0 = *(const short8*)(qr + quad * 8);
    short8 qf1 = *(const short8*)(qr + 32 + quad * 8);

    float4v o[4] = {};
    float lsum = 0.f;
    int nt = xt + 1;

    uint4 ka, kb2, va, vb;
    {
        const unsigned short* gk = Kp + baseQ + (size_t)row4 * HDIM + seg * 16;
        const unsigned short* gv = Vt + baseV + (size_t)row4 * T_SEQ + seg * 16;
        ka = *(const uint4*)gk; kb2 = *(const uint4*)(gk + 8);
        va = *(const uint4*)gv; vb = *(const uint4*)(gv + 8);
    }
    *(uint4*)(sK[0] + row4 * 72 + seg * 16) = ka;
    *(uint4*)(sK[0] + row4 * 72 + seg * 16 + 8) = kb2;
    *(uint4*)(sV[0] + row4 * 72 + seg * 16) = va;
    *(uint4*)(sV[0] + row4 * 72 + seg * 16 + 8) = vb;

    for (int t = 0; t < nt; t++) {
        int cur = t & 1;
        __syncthreads();
        if (t + 1 < nt) {
            const unsigned short* gk =
                Kp + baseQ + (size_t)((t + 1) * 64 + row4) * HDIM + seg * 16;
            const unsigned short* gv =
                Vt + baseV + (size_t)row4 * T_SEQ + (t + 1) * 64 + seg * 16;
            ka = *(const uint4*)gk; kb2 = *(const uint4*)(gk + 8);
            va = *(const uint4*)gv; vb = *(const uint4*)(gv + 8);
        }

        const unsigned short* cK = sK[cur];
        const unsigned short* cV = sV[cur];
        float4v s[4];
        for (int sub = 0; sub < 4; sub++) {
            short8 kf0 = *(const short8*)(cK + (sub * 16 + l16) * 72 + quad * 8);
            short8 kf1 =
                *(const short8*)(cK + (sub * 16 + l16) * 72 + 32 + quad * 8);
            float4v z = {};
            z = __builtin_amdgcn_mfma_f32_16x16x32_bf16(kf0, qf0, z, 0, 0, 0);
            z = __builtin_amdgcn_mfma_f32_16x16x32_bf16(kf1, qf1, z, 0, 0, 0);
            s[sub] = z;
        }

        bool need_mask = (t * 64 + 63) > (qb + wave * 16);  // wave-uniform
        float p[16];
        for (int sub = 0; sub < 4; sub++)
            for (int r = 0; r < 4; r++) {
                float v = s[sub][r];
                if (need_mask) {
                    int kg = t * 64 + sub * 16 + quad * 4 + r;
                    v = (kg <= qrow) ? v : -1e30f;
                }
                p[sub * 4 + r] = v;
            }
        unsigned ub[16];
        for (int i = 0; i < 16; i++) {
            float e = exp2f(p[i] - 16.0f);
            unsigned u = __builtin_bit_cast(unsigned, e) & 0xffff0000u;
            ub[i] = u;
            lsum += __builtin_bit_cast(float, u);
        }

        for (int sub = 0; sub < 4; sub++) {
            unsigned lo = __builtin_amdgcn_perm(ub[sub * 4 + 1], ub[sub * 4 + 0],
                                                0x07060302u);
            unsigned hi = __builtin_amdgcn_perm(ub[sub * 4 + 3], ub[sub * 4 + 2],
                                                0x07060302u);
            uint2 packed = {lo, hi};
            short4v pf = __builtin_bit_cast(short4v, packed);
            for (int dc = 0; dc < 4; dc++) {
                short4v vf = *(const short4v*)(
                    cV + (dc * 16 + l16) * 72 + sub * 16 + quad * 4);
                o[dc] = __builtin_amdgcn_mfma_f32_16x16x16bf16_1k(
                    vf, pf, o[dc], 0, 0, 0);
            }
        }

        if (t + 1 < nt) {
            int nxt = cur ^ 1;
            *(uint4*)(sK[nxt] + row4 * 72 + seg * 16) = ka;
            *(uint4*)(sK[nxt] + row4 * 72 + seg * 16 + 8) = kb2;
            *(uint4*)(sV[nxt] + row4 * 72 + seg * 16) = va;
            *(uint4*)(sV[nxt] + row4 * 72 + seg * 16 + 8) = vb;
        }
    }

    lsum += __shfl_xor(lsum, 16);
    lsum += __shfl_xor(lsum, 32);
    float inv = 1.0f / lsum;

    __syncthreads();
    for (int dc = 0; dc < 4; dc++) {
        short4v ov;
        for (int r = 0; r < 4; r++) ov[r] = (short)f2bf(o[dc][r] * inv);
        *(short4v*)(sK[0] + wave * 1152 + l16 * 72 + dc * 16 + quad * 4) = ov;
    }
    __syncthreads();
    int orow = lane >> 2, oseg = lane & 3;
    uint4 a = *(const uint4*)(sK[0] + wave * 1152 + orow * 72 + oseg * 16);
    uint4 b = *(const uint4*)(sK[0] + wave * 1152 + orow * 72 + oseg * 16 + 8);
    unsigned short* dst = att +
        (size_t)(bb * T_SEQ + qb + wave * 16 + orow) * CDIM + h * HDIM +
        oseg * 16;
    *(uint4*)dst = a;
    *(uint4*)(dst + 8) = b;
}

// ---------------- launch ----------------
extern "C" void kernel_launch(void* const* d_in, const int* in_sizes, int n_in,
                              void* d_out, int out_size, void* d_ws, size_t ws_size,
                              hipStream_t stream) {
    const float* x      = (const float*)d_in[0];   // [2,2048,1024]
    const float* W_attn = (const float*)d_in[1];   // [1024,3072]
    const float* W_proj = (const float*)d_in[2];   // [1024,1024]
    const float* b_proj = (const float*)d_in[3];   // [1024]
    float* out = (float*)d_out;                    // [2,2048,1024]

    unsigned short* xb   = (unsigned short*)d_ws;          // 4096*1024
    unsigned short* WaT  = xb  + 4096 * 1024;              // 3072*1024 (transposed)
    unsigned short* WpT  = WaT + 3072 * 1024;              // 1024*1024 (transposed)
    unsigned short* Karr = WpT + 1024 * 1024;              // [B,H,T,64]
    unsigned short* Qarr = Karr + 2 * 16 * 2048 * 64;      // [B,H,T,64] pre-scaled
    unsigned short* Varr = Qarr + 2 * 16 * 2048 * 64;      // [B,H,64,T] transposed
    unsigned short* attb = Varr + 2 * 16 * 2048 * 64;      // 4096*1024

    convert_f32_bf16_vec<<<4096, 256, 0, stream>>>(x, xb);
    transpose_f32_bf16<<<dim3(32, 96), 256, 0, stream>>>(W_attn, WaT, 1024, 3072);
    transpose_f32_bf16<<<dim3(32, 32), 256, 0, stream>>>(W_proj, WpT, 1024, 1024);
    gemm_qkv<<<dim3(24, 32), 256, 0, stream>>>(xb, WaT, Karr, Qarr, Varr);
    attn_fwd<<<dim3(32, 32), 256, 0, stream>>>(Qarr, Karr, Varr, attb);
    gemm_proj<<<dim3(16, 64), 256, 0, stream>>>(attb, WpT, b_proj, out);
}